// Round 1
// baseline (110.714 us; speedup 1.0000x reference)
//
#include <hip/hip_runtime.h>

constexpr int N    = 256;
constexpr int OUT  = 32;
constexpr int M2   = 32896;     // C(257,2)
constexpr int M3   = 2829056;   // C(258,3)
constexpr int NB3  = 1024;      // blocks for deg-3
constexpr int NB2  = 64;        // blocks for deg-2
constexpr int NBTOT = NB3 + NB2;

__device__ __forceinline__ int c3_tail(int s) {
    // number of lex triples with first element >= i, s = n - i
    return s * (s + 1) * (s + 2) / 6;
}

__global__ __launch_bounds__(256) void poly_partial(
    const float* __restrict__ x, const float* __restrict__ c2,
    const float* __restrict__ c3, float* __restrict__ partial)
{
    __shared__ float xs[N];
    const int tid = threadIdx.x;
    if (tid < N) xs[tid] = x[tid];
    __syncthreads();

    float acc[OUT];
#pragma unroll
    for (int o = 0; o < OUT; ++o) acc[o] = 0.f;

    if (blockIdx.x < NB3) {
        // ---- degree-3 term: 32 x 2,829,056 coefficients ----
        const int stride = NB3 * 256 * 4;
        for (int base = ((int)blockIdx.x * 256 + tid) * 4; base < M3; base += stride) {
            // decode base -> (i,j,k), i<=j<=k, lexicographic multiset order
            int lo = 0, hi = N - 1;
            while (lo < hi) {                       // find i
                int mid = (lo + hi + 1) >> 1;
                int O = M3 - c3_tail(N - mid);
                if (O <= base) lo = mid; else hi = mid - 1;
            }
            int i = lo;
            int s = N - i;
            int rem = base - (M3 - c3_tail(s));
            lo = 0; hi = s - 1;
            while (lo < hi) {                       // find a = j - i
                int mid = (lo + hi + 1) >> 1;
                int A = mid * s - (mid * (mid - 1)) / 2;
                if (A <= rem) lo = mid; else hi = mid - 1;
            }
            int a = lo;
            int b = rem - (a * s - (a * (a - 1)) / 2);
            int j = i + a, k = j + b;

            float v[4];
#pragma unroll
            for (int t = 0; t < 4; ++t) {
                v[t] = xs[i] * xs[j] * xs[k];
                ++k;                                 // advance to next multiset
                if (k == N) { ++j; if (j == N) { ++i; j = i; } k = j; }
            }
#pragma unroll
            for (int o = 0; o < OUT; ++o) {
                const float4 c = *reinterpret_cast<const float4*>(
                    c3 + (size_t)o * M3 + base);
                acc[o] += c.x * v[0] + c.y * v[1] + c.z * v[2] + c.w * v[3];
            }
        }
    } else {
        // ---- degree-2 term: 32 x 32,896 coefficients ----
        const int bid = (int)blockIdx.x - NB3;
        const int stride = NB2 * 256 * 4;
        for (int base = (bid * 256 + tid) * 4; base < M2; base += stride) {
            int lo = 0, hi = N - 1;
            while (lo < hi) {                       // find j
                int mid = (lo + hi + 1) >> 1;
                int O = mid * N - (mid * (mid - 1)) / 2;
                if (O <= base) lo = mid; else hi = mid - 1;
            }
            int j = lo;
            int k = j + (base - (j * N - (j * (j - 1)) / 2));
            float v[4];
#pragma unroll
            for (int t = 0; t < 4; ++t) {
                v[t] = xs[j] * xs[k];
                ++k;
                if (k == N) { ++j; k = j; }
            }
#pragma unroll
            for (int o = 0; o < OUT; ++o) {
                const float4 c = *reinterpret_cast<const float4*>(
                    c2 + (size_t)o * M2 + base);
                acc[o] += c.x * v[0] + c.y * v[1] + c.z * v[2] + c.w * v[3];
            }
        }
    }

    // ---- block reduction: 4 waves x 64 lanes -> partial[block][o] ----
    __shared__ float red[4][OUT];
    const int lane = tid & 63, wid = tid >> 6;
#pragma unroll
    for (int o = 0; o < OUT; ++o) {
        float a = acc[o];
#pragma unroll
        for (int off = 32; off > 0; off >>= 1) a += __shfl_down(a, off);
        if (lane == 0) red[wid][o] = a;
    }
    __syncthreads();
    if (tid < OUT) {
        partial[(size_t)blockIdx.x * OUT + tid] =
            red[0][tid] + red[1][tid] + red[2][tid] + red[3][tid];
    }
}

__global__ __launch_bounds__(256) void poly_final(
    const float* __restrict__ partial, const float* __restrict__ x,
    const float* __restrict__ c0, const float* __restrict__ c1,
    float* __restrict__ out)
{
    __shared__ float lds[256];
    const int tid = threadIdx.x;
    const int o = tid & 31, g = tid >> 5;          // 8 groups x 32 outputs
    float a = 0.f;
    for (int b = g; b < NBTOT; b += 8)
        a += partial[(size_t)b * OUT + o];
    for (int k = g * 32; k < g * 32 + 32; ++k)     // degree-1 term
        a += c1[o * N + k] * x[k];
    if (g == 0) a += c0[o];                        // degree-0 term
    lds[tid] = a;
    __syncthreads();
    if (g == 0) {
        float s = 0.f;
#pragma unroll
        for (int gg = 0; gg < 8; ++gg) s += lds[o + 32 * gg];
        out[o] = s;
    }
}

extern "C" void kernel_launch(void* const* d_in, const int* in_sizes, int n_in,
                              void* d_out, int out_size, void* d_ws, size_t ws_size,
                              hipStream_t stream) {
    const float* x  = (const float*)d_in[0];
    const float* c0 = (const float*)d_in[1];
    const float* c1 = (const float*)d_in[2];
    const float* c2 = (const float*)d_in[3];
    const float* c3 = (const float*)d_in[4];
    float* out     = (float*)d_out;
    float* partial = (float*)d_ws;   // NBTOT * 32 floats = 139 KB

    poly_partial<<<NBTOT, 256, 0, stream>>>(x, c2, c3, partial);
    poly_final<<<1, 256, 0, stream>>>(partial, x, c0, c1, out);
}

// Round 2
// 81.102 us; speedup vs baseline: 1.3651x; 1.3651x over previous
//
#include <hip/hip_runtime.h>

constexpr int N   = 256;
constexpr int OUT = 32;
constexpr int OPG = 8;          // outputs per o-group
constexpr int OG  = OUT / OPG;  // 4 o-groups
constexpr int M2  = 32896;      // C(257,2)
constexpr int M3  = 2829056;    // C(258,3)
constexpr int Q3  = M3 / 4;     // 707264 float4-quads
constexpr int Q2  = M2 / 4;     // 8224
constexpr int B3  = 691;        // deg-3 blocks per o-group (4 grid-stride iters)
constexpr int B2  = 33;         // deg-2 blocks per o-group (1 quad/thread)
constexpr int BX  = B3 + B2;    // 724 blocks in x; grid = (724, 4)

__device__ __forceinline__ int c3_tail(int s) {
    // # of ordered triples from s values = C(s+2,3)
    return s * (s + 1) * (s + 2) / 6;
}

__global__ __launch_bounds__(256) void poly_partial(
    const float* __restrict__ x, const float* __restrict__ c2,
    const float* __restrict__ c3, float* __restrict__ partial)
{
    __shared__ float xs[N];
    const int tid = threadIdx.x;
    if (tid < N) xs[tid] = x[tid];
    __syncthreads();

    const int g     = blockIdx.y;          // outputs g*8 .. g*8+7
    const int obase = g * OPG;

    float acc[OPG];
#pragma unroll
    for (int oo = 0; oo < OPG; ++oo) acc[oo] = 0.f;

    if ((int)blockIdx.x < B3) {
        // ---- degree-3: 8 coalesced float4 streams per wave-iteration ----
        for (int it = 0; it < 4; ++it) {
            const int q = (int)blockIdx.x * 256 + tid + it * (B3 * 256);
            if (q >= Q3) break;
            const int base = q * 4;

            // decode base -> (i,j,k), i<=j<=k, lexicographic multiset order
            int lo = 0, hi = N - 1;
            while (lo < hi) {                       // find i
                int mid = (lo + hi + 1) >> 1;
                int O = M3 - c3_tail(N - mid);
                if (O <= base) lo = mid; else hi = mid - 1;
            }
            const int i = lo;
            const int s = N - i;
            const int rem = base - (M3 - c3_tail(s));
            lo = 0; hi = s - 1;
            while (lo < hi) {                       // find a = j - i
                int mid = (lo + hi + 1) >> 1;
                int A = mid * s - (mid * (mid - 1)) / 2;
                if (A <= rem) lo = mid; else hi = mid - 1;
            }
            const int a = lo;
            int j = i + a, k = j + (rem - (a * s - (a * (a - 1)) / 2));
            int ii = i;

            float v[4];
#pragma unroll
            for (int t = 0; t < 4; ++t) {
                v[t] = xs[ii] * xs[j] * xs[k];
                ++k;                                 // next multiset
                if (k == N) { ++j; if (j == N) { ++ii; j = ii; } k = j; }
            }
            const float* p = c3 + (size_t)obase * M3 + base;
#pragma unroll
            for (int oo = 0; oo < OPG; ++oo) {
                const float4 c = *reinterpret_cast<const float4*>(p + (size_t)oo * M3);
                acc[oo] += c.x * v[0] + c.y * v[1] + c.z * v[2] + c.w * v[3];
            }
        }
    } else {
        // ---- degree-2 ----
        const int q = ((int)blockIdx.x - B3) * 256 + tid;
        if (q < Q2) {
            const int base = q * 4;
            int lo = 0, hi = N - 1;
            while (lo < hi) {                       // find j
                int mid = (lo + hi + 1) >> 1;
                int O = mid * N - (mid * (mid - 1)) / 2;
                if (O <= base) lo = mid; else hi = mid - 1;
            }
            int j = lo;
            int k = j + (base - (j * N - (j * (j - 1)) / 2));
            float v[4];
#pragma unroll
            for (int t = 0; t < 4; ++t) {
                v[t] = xs[j] * xs[k];
                ++k;
                if (k == N) { ++j; k = j; }
            }
            const float* p = c2 + (size_t)obase * M2 + base;
#pragma unroll
            for (int oo = 0; oo < OPG; ++oo) {
                const float4 c = *reinterpret_cast<const float4*>(p + (size_t)oo * M2);
                acc[oo] += c.x * v[0] + c.y * v[1] + c.z * v[2] + c.w * v[3];
            }
        }
    }

    // ---- block reduction: 4 waves -> partial[(g*BX + bx)*8 + oo] ----
    __shared__ float red[4][OPG];
    const int lane = tid & 63, wid = tid >> 6;
#pragma unroll
    for (int oo = 0; oo < OPG; ++oo) {
        float a = acc[oo];
#pragma unroll
        for (int off = 32; off > 0; off >>= 1) a += __shfl_down(a, off);
        if (lane == 0) red[wid][oo] = a;
    }
    __syncthreads();
    if (tid < OPG) {
        partial[((size_t)g * BX + blockIdx.x) * OPG + tid] =
            red[0][tid] + red[1][tid] + red[2][tid] + red[3][tid];
    }
}

__global__ __launch_bounds__(1024) void poly_final(
    const float* __restrict__ partial, const float* __restrict__ x,
    const float* __restrict__ c0, const float* __restrict__ c1,
    float* __restrict__ out)
{
    __shared__ float lds[1024];
    const int tid = threadIdx.x;
    const int o = tid & 31, c = tid >> 5;          // 32 chunks x 32 outputs
    const int g = o >> 3, oo = o & 7;

    float a = 0.f;
    for (int b = c; b < BX; b += 32)               // partial sums
        a += partial[((size_t)g * BX + b) * OPG + oo];
#pragma unroll
    for (int e = 0; e < 8; ++e) {                  // degree-1 term
        const int k = c * 8 + e;
        a += c1[o * N + k] * x[k];
    }
    if (c == 0) a += c0[o];                        // degree-0 term
    lds[tid] = a;
    __syncthreads();
    if (tid < 32) {
        float s = 0.f;
#pragma unroll
        for (int cc = 0; cc < 32; ++cc) s += lds[cc * 32 + tid];
        out[tid] = s;
    }
}

extern "C" void kernel_launch(void* const* d_in, const int* in_sizes, int n_in,
                              void* d_out, int out_size, void* d_ws, size_t ws_size,
                              hipStream_t stream) {
    const float* x  = (const float*)d_in[0];
    const float* c0 = (const float*)d_in[1];
    const float* c1 = (const float*)d_in[2];
    const float* c2 = (const float*)d_in[3];
    const float* c3 = (const float*)d_in[4];
    float* out     = (float*)d_out;
    float* partial = (float*)d_ws;   // OG*BX*OPG = 23168 floats = 92.7 KB

    dim3 grid(BX, OG);
    poly_partial<<<grid, 256, 0, stream>>>(x, c2, c3, partial);
    poly_final<<<1, 1024, 0, stream>>>(partial, x, c0, c1, out);
}

// Round 3
// 69.412 us; speedup vs baseline: 1.5950x; 1.1684x over previous
//
#include <hip/hip_runtime.h>

constexpr int N   = 256;
constexpr int OUT = 32;
constexpr int OPG = 8;           // outputs per o-group
constexpr int OG  = OUT / OPG;   // 4 o-groups
constexpr int M2  = 32896;       // C(257,2)
constexpr int M3  = 2829056;     // C(258,3)
constexpr int Q3  = M3 / 4;      // 707264 float4-quads
constexpr int Q2  = M2 / 4;      // 8224
constexpr int BX  = 256;         // blocks per o-group; grid = (256,4) = 1024 blocks
constexpr int IT3 = 11;          // ceil(Q3 / (BX*256))
constexpr int D2_FIRST = 208;    // blocks [208,256) also handle deg-2 (idle in deg-3 it=10)

typedef float f32x4 __attribute__((ext_vector_type(4)));

__device__ __forceinline__ int c3_tail(int s) {
    return s * (s + 1) * (s + 2) / 6;   // C(s+2,3)
}

__global__ __launch_bounds__(256, 4) void poly_partial(
    const float* __restrict__ x, const float* __restrict__ c2,
    const float* __restrict__ c3, float* __restrict__ partial)
{
    __shared__ float xs[N];
    const int tid = threadIdx.x;
    if (tid < N) xs[tid] = x[tid];
    __syncthreads();

    const int bx = blockIdx.x;
    const int g  = blockIdx.y;               // outputs g*8 .. g*8+7

    float acc[OPG];
#pragma unroll
    for (int oo = 0; oo < OPG; ++oo) acc[oo] = 0.f;

    const float* __restrict__ c3g = c3 + (size_t)g * OPG * M3;

    // ---- degree-3: 11 guarded iterations, all 1024 blocks co-resident ----
    for (int it = 0; it < IT3; ++it) {
        const int q = bx * 256 + tid + it * (BX * 256);
        if (q < Q3) {
            const int base = q * 4;
            // decode base -> (i,j,k), i<=j<=k, lex multiset order
            int lo = 0, hi = N - 1;
            while (lo < hi) {                       // find i
                int mid = (lo + hi + 1) >> 1;
                int O = M3 - c3_tail(N - mid);
                if (O <= base) lo = mid; else hi = mid - 1;
            }
            const int i = lo;
            const int s = N - i;
            const int rem = base - (M3 - c3_tail(s));
            lo = 0; hi = s - 1;
            while (lo < hi) {                       // find a = j - i
                int mid = (lo + hi + 1) >> 1;
                int A = mid * s - (mid * (mid - 1)) / 2;
                if (A <= rem) lo = mid; else hi = mid - 1;
            }
            const int a = lo;
            int ii = i, j = i + a, k = j + (rem - (a * s - (a * (a - 1)) / 2));

            float v[4];
#pragma unroll
            for (int t = 0; t < 4; ++t) {
                v[t] = xs[ii] * xs[j] * xs[k];
                ++k;                                 // next multiset
                if (k == N) { ++j; if (j == N) { ++ii; j = ii; } k = j; }
            }
            const float* p = c3g + base;
#pragma unroll
            for (int oo = 0; oo < OPG; ++oo) {
                const f32x4 c = __builtin_nontemporal_load(
                    reinterpret_cast<const f32x4*>(p + (size_t)oo * M3));
                acc[oo] += c[0] * v[0] + c[1] * v[1] + c[2] * v[2] + c[3] * v[3];
            }
        }
    }

    // ---- degree-2: handled by blocks idle in deg-3's ragged last iteration ----
    if (bx >= D2_FIRST) {
        const int q = (bx - D2_FIRST) * 256 + tid;
        if (q < Q2) {
            const int base = q * 4;
            int lo = 0, hi = N - 1;
            while (lo < hi) {                       // find j
                int mid = (lo + hi + 1) >> 1;
                int O = mid * N - (mid * (mid - 1)) / 2;
                if (O <= base) lo = mid; else hi = mid - 1;
            }
            int j = lo;
            int k = j + (base - (j * N - (j * (j - 1)) / 2));
            float v[4];
#pragma unroll
            for (int t = 0; t < 4; ++t) {
                v[t] = xs[j] * xs[k];
                ++k;
                if (k == N) { ++j; k = j; }
            }
            const float* p = c2 + (size_t)g * OPG * M2 + base;
#pragma unroll
            for (int oo = 0; oo < OPG; ++oo) {
                const f32x4 c = __builtin_nontemporal_load(
                    reinterpret_cast<const f32x4*>(p + (size_t)oo * M2));
                acc[oo] += c[0] * v[0] + c[1] * v[1] + c[2] * v[2] + c[3] * v[3];
            }
        }
    }

    // ---- block reduction: 4 waves -> partial[(g*BX+bx)*8 + oo] ----
    __shared__ float red[4][OPG];
    const int lane = tid & 63, wid = tid >> 6;
#pragma unroll
    for (int oo = 0; oo < OPG; ++oo) {
        float a = acc[oo];
#pragma unroll
        for (int off = 32; off > 0; off >>= 1) a += __shfl_down(a, off);
        if (lane == 0) red[wid][oo] = a;
    }
    __syncthreads();
    if (tid < OPG) {
        partial[((size_t)g * BX + bx) * OPG + tid] =
            red[0][tid] + red[1][tid] + red[2][tid] + red[3][tid];
    }
}

__global__ __launch_bounds__(1024) void poly_final(
    const float* __restrict__ partial, const float* __restrict__ x,
    const float* __restrict__ c0, const float* __restrict__ c1,
    float* __restrict__ out)
{
    __shared__ float lds[1024];
    const int tid = threadIdx.x;
    const int o = tid & 31, c = tid >> 5;          // 32 chunks x 32 outputs
    const int g = o >> 3, oo = o & 7;

    float a = 0.f;
#pragma unroll
    for (int r = 0; r < BX / 32; ++r) {            // 8 partials per thread
        const int b = c + r * 32;
        a += partial[((size_t)g * BX + b) * OPG + oo];
    }
#pragma unroll
    for (int e = 0; e < 8; ++e) {                  // degree-1 term
        const int k = c * 8 + e;
        a += c1[o * N + k] * x[k];
    }
    if (c == 0) a += c0[o];                        // degree-0 term
    lds[tid] = a;
    __syncthreads();
    if (tid < 32) {
        float s = 0.f;
#pragma unroll
        for (int cc = 0; cc < 32; ++cc) s += lds[cc * 32 + tid];
        out[tid] = s;
    }
}

extern "C" void kernel_launch(void* const* d_in, const int* in_sizes, int n_in,
                              void* d_out, int out_size, void* d_ws, size_t ws_size,
                              hipStream_t stream) {
    const float* x  = (const float*)d_in[0];
    const float* c0 = (const float*)d_in[1];
    const float* c1 = (const float*)d_in[2];
    const float* c2 = (const float*)d_in[3];
    const float* c3 = (const float*)d_in[4];
    float* out     = (float*)d_out;
    float* partial = (float*)d_ws;   // OG*BX*OPG = 8192 floats = 32 KB

    dim3 grid(BX, OG);
    poly_partial<<<grid, 256, 0, stream>>>(x, c2, c3, partial);
    poly_final<<<1, 1024, 0, stream>>>(partial, x, c0, c1, out);
}